// Round 11
// baseline (134.380 us; speedup 1.0000x reference)
//
#include <hip/hip_runtime.h>
#include <cfloat>
#include <cstddef>

#define NBATCH 2
#define NPTS   5000
#define NF     64
#define NB     10      // bins = N / BIN_SIZE
#define BINSZ  500
#define TOPK   5
#define ROTCOLS 100    // MAX_NUM_BINS/2 columns in rotations

#define NZ     3500                         // zero-ballast blocks in K1
#define OUT4   (NBATCH * NPTS * NPTS / 4)   // 12.5M float4 in d_out
#define CPW    63                           // cols per wave (8 waves x 63 >= 500)

// ---------------------------------------------------------------------------
// K1: blocks [0,2) = FUSED per-batch {bin+norm (thread-per-point, rot in LDS)
//     + stable counting sort (validated phases verbatim)}; blocks [2,2+NZ) =
//     zero d_out (plain stores, R5-style). Compute hides under the zero.
// ---------------------------------------------------------------------------
__global__ __launch_bounds__(256) void binsort_zero_k(const float* __restrict__ pts,
                                                      const float* __restrict__ rot,
                                                      float* __restrict__ na,
                                                      int* __restrict__ order,
                                                      float* __restrict__ out) {
    const int t = threadIdx.x;
    if (blockIdx.x >= NBATCH) {              // ---- zero-stream path ----
        const int z = blockIdx.x - NBATCH;
        const int chunk = (OUT4 + NZ - 1) / NZ;            // 3572
        const size_t base = (size_t)z * chunk;
        size_t end = base + chunk; if (end > (size_t)OUT4) end = OUT4;
        float4* o4 = (float4*)out;
        const float4 z4 = make_float4(0.f, 0.f, 0.f, 0.f);
        for (size_t i = base + t; i < end; i += 256) o4[i] = z4;
        return;
    }

    // ---- fused bin+norm+sort path (one block per batch) ----
    const int b = blockIdx.x;
    const int w = t >> 6, lane = t & 63;
    __shared__ int   sh_bin[NPTS];           // 20 KB
    __shared__ int   sh_hist[256][NB];       // 10.24 KB
    __shared__ int   sh_part[NB][16];
    __shared__ int   sh_tot[NB + 1];
    __shared__ float srot[NF * 5];           // 1.25 KB

    for (int i = t; i < NF * 5; i += 256) {  // full 320-element fill
        int f = i / 5, h = i - 5 * f;
        srot[i] = rot[f * ROTCOLS + h];
    }
    #pragma unroll
    for (int h = 0; h < NB; ++h) sh_hist[t][h] = 0;
    __syncthreads();

    const int CH = (NPTS + 255) / 256;       // 20
    const int i0 = t * CH;
    const int i1 = (i0 + CH < NPTS) ? (i0 + CH) : NPTS;
    const float4* p4 = (const float4*)(pts + (size_t)b * NPTS * NF);

    for (int i = i0; i < i1; ++i) {          // bin + norm, thread-per-point
        float nn = 0.f, c0 = 0.f, c1 = 0.f, c2 = 0.f, c3 = 0.f, c4 = 0.f;
        #pragma unroll
        for (int q = 0; q < 16; ++q) {
            float4 v = p4[(size_t)i * 16 + q];
            const float* s0 = &srot[(4 * q) * 5];     // uniform LDS broadcasts
            nn += v.x * v.x; nn += v.y * v.y; nn += v.z * v.z; nn += v.w * v.w;
            c0 += v.x * s0[0];  c1 += v.x * s0[1];  c2 += v.x * s0[2];  c3 += v.x * s0[3];  c4 += v.x * s0[4];
            c0 += v.y * s0[5];  c1 += v.y * s0[6];  c2 += v.y * s0[7];  c3 += v.y * s0[8];  c4 += v.y * s0[9];
            c0 += v.z * s0[10]; c1 += v.z * s0[11]; c2 += v.z * s0[12]; c3 += v.z * s0[13]; c4 += v.z * s0[14];
            c0 += v.w * s0[15]; c1 += v.w * s0[16]; c2 += v.w * s0[17]; c3 += v.w * s0[18]; c4 += v.w * s0[19];
        }
        na[b * NPTS + i] = nn;
        float c[5] = {c0, c1, c2, c3, c4};
        float bv = c[0]; int bi = 0;
        #pragma unroll
        for (int h = 1; h < 5; ++h) if (c[h] > bv) { bv = c[h]; bi = h; }
        #pragma unroll
        for (int h = 0; h < 5; ++h) if (-c[h] > bv) { bv = -c[h]; bi = h + 5; }
        sh_bin[i] = bi;                      // first-max wins, matches jnp.argmax
        sh_hist[t][bi]++;
    }
    __syncthreads();

    if (t < NB * 16) {                       // segment partial sums
        int h = t >> 4, s = t & 15;
        int sum = 0;
        #pragma unroll
        for (int k = 0; k < 16; ++k) sum += sh_hist[s * 16 + k][h];
        sh_part[h][s] = sum;
    }
    __syncthreads();
    if (t < NB) {
        int tot = 0;
        #pragma unroll
        for (int s = 0; s < 16; ++s) tot += sh_part[t][s];
        sh_tot[t + 1] = tot;
    }
    __syncthreads();
    if (t == 0) {
        sh_tot[0] = 0;
        for (int h = 1; h <= NB; ++h) sh_tot[h] += sh_tot[h - 1];
    }
    __syncthreads();

    for (int h = w; h < NB; h += 4) {        // wave-parallel exclusive scan
        int base = lane * 4;
        int v0 = sh_hist[base + 0][h];
        int v1 = sh_hist[base + 1][h];
        int v2 = sh_hist[base + 2][h];
        int v3 = sh_hist[base + 3][h];
        int lt = v0 + v1 + v2 + v3;
        int x = lt;
        #pragma unroll
        for (int off = 1; off < 64; off <<= 1) {
            int y = __shfl_up(x, off);
            if (lane >= off) x += y;
        }
        int excl = x - lt + sh_tot[h];
        sh_hist[base + 0][h] = excl;
        sh_hist[base + 1][h] = excl + v0;
        sh_hist[base + 2][h] = excl + v0 + v1;
        sh_hist[base + 3][h] = excl + v0 + v1 + v2;
    }
    __syncthreads();

    for (int i = i0; i < i1; ++i) {          // stable placement
        int h = sh_bin[i];
        order[b * NPTS + sh_hist[t][h]++] = i;
    }
}

// ---------------------------------------------------------------------------
// K2: readlane-gram + in-block 8-way merge + inject (R10-validated verbatim).
// Grid: 20 groups x 8 row-blocks = 160 blocks of 512 threads.
// ---------------------------------------------------------------------------
__global__ __launch_bounds__(512) void pair_merge_inject_k(const float* __restrict__ pts,
                                                           const float* __restrict__ na,
                                                           const int* __restrict__ order,
                                                           float* __restrict__ out) {
    const int bx   = blockIdx.x;
    const int g    = bx >> 3;        // 0..19
    const int rb   = bx & 7;         // row-block 0..7
    const int b    = g / NB;
    const int grp  = g - b * NB;
    const int tid  = threadIdx.x;
    const int w    = tid >> 6;       // wave 0..7 (col partition)
    const int lane = tid & 63;

    __shared__ float sh_mv[8][64][TOPK];
    __shared__ int   sh_mi[8][64][TOPK];

    const int* ord = order + b * NPTS + grp * BINSZ;
    const float*  pb  = pts + (size_t)b * NPTS * NF;
    const float4* p4  = (const float4*)pb;
    const float*  nab = na + b * NPTS;

    const int prow = rb * 64 + lane;
    const int pcl  = (prow < BINSZ) ? prow : (BINSZ - 1);  // clamp; never written
    const int gi   = ord[pcl];
    float4 r[16];
    #pragma unroll
    for (int q = 0; q < 16; ++q) r[q] = p4[(size_t)gi * 16 + q];
    const float* rf = (const float*)r;                     // static-indexed below
    const float na_r = nab[gi];

    float tv[TOPK]; int tp[TOPK];
    #pragma unroll
    for (int s = 0; s < TOPK; ++s) { tv[s] = FLT_MAX; tp[s] = 0; }

    const int c_lo = w * CPW;
    const int c_hi = (c_lo + CPW < BINSZ) ? (c_lo + CPW) : BINSZ;  // last wave: 59
    for (int cj = c_lo; cj < c_hi; ++cj) {
        const int gc = ord[cj];                 // uniform across wave
        const float colv = pb[(size_t)gc * NF + lane];   // coalesced 256B
        const float cna  = nab[gc];
        float acc = 0.f;
        #pragma unroll
        for (int k = 0; k < 64; ++k) {          // readlane -> SGPR operand FMA
            float bc = __uint_as_float(__builtin_amdgcn_readlane(__float_as_uint(colv), k));
            acc += rf[k] * bc;
        }
        float d2 = na_r - 2.f * acc + cna;
        if (d2 < tv[TOPK - 1]) {                // strict <: ties keep earlier pos
            tv[TOPK - 1] = d2; tp[TOPK - 1] = cj;
            #pragma unroll
            for (int s = TOPK - 1; s > 0; --s) {
                if (tv[s] < tv[s - 1]) {
                    float fv = tv[s]; tv[s] = tv[s - 1]; tv[s - 1] = fv;
                    int   fi = tp[s]; tp[s] = tp[s - 1]; tp[s - 1] = fi;
                }
            }
        }
    }

    #pragma unroll
    for (int s = 0; s < TOPK; ++s) { sh_mv[w][lane][s] = tv[s]; sh_mi[w][lane][s] = tp[s]; }
    __syncthreads();

    if (tid < 64) {
        const int r_ = tid;
        const int my = rb * 64 + r_;
        if (my < BINSZ) {
            int h[8] = {0, 0, 0, 0, 0, 0, 0, 0};
            const int src = ord[my];
            float* orow = out + ((size_t)b * NPTS + src) * NPTS;
            #pragma unroll
            for (int s = 0; s < TOPK; ++s) {
                float best = sh_mv[0][r_][h[0]]; int bw = 0;
                #pragma unroll
                for (int ww = 1; ww < 8; ++ww) {
                    float v = sh_mv[ww][r_][h[ww]];
                    if (v < best) { best = v; bw = ww; }   // ties -> lower wave = earlier pos
                }
                const int j = sh_mi[bw][r_][h[bw]];
                h[bw]++;
                float val = expf(-0.1f * sqrtf(fmaxf(best, 1e-6f)));
                orow[ord[j]] = val;
            }
        }
    }
}

// ---------------------------------------------------------------------------
extern "C" void kernel_launch(void* const* d_in, const int* in_sizes, int n_in,
                              void* d_out, int out_size, void* d_ws, size_t ws_size,
                              hipStream_t stream) {
    const float* points = (const float*)d_in[0];
    const float* rot    = (const float*)d_in[1];
    float* out = (float*)d_out;

    char* ws = (char*)d_ws;
    float* na    = (float*)ws; ws += NBATCH * NPTS * sizeof(float);
    int*   order = (int*)ws;   // ~80 KB total

    binsort_zero_k<<<NBATCH + NZ, 256, 0, stream>>>(points, rot, na, order, out);
    pair_merge_inject_k<<<NBATCH * NB * 8, 512, 0, stream>>>(points, na, order, out);
}